// Round 4
// baseline (327.918 us; speedup 1.0000x reference)
//
#include <hip/hip_runtime.h>

// Patcher: x (8,3,1024,1024) fp32, patch_size=24, stride=16, reflect pad m=4.
// Output: patches (32768, 576, 3) fp32 + scalars nH=nW=64.
// One workgroup per patch: float4 global loads -> planar LDS -> float4
// nontemporal coalesced stores of the channel-interleaved output.
// Block->patch swizzle: blockIdx % 8 (the XCD under round-robin dispatch)
// selects the batch image, so all patch-overlap reuse is XCD-L2-local.

typedef float vfloat4 __attribute__((ext_vector_type(4)));

constexpr int PS  = 24;
constexpr int QTOT = PS * PS;                 // 576
constexpr int PATCH_F = QTOT * 3;             // 1728 floats per patch
constexpr int NPATCH = 8 * 64 * 64;           // 32768
constexpr int PATCH_ELEMS_I = NPATCH * PATCH_F; // 56,623,104
constexpr int NV = PATCH_F / 4;               // 432 float4 per patch

__global__ __launch_bounds__(256) void patcher_kernel(
    const float* __restrict__ x, float* __restrict__ out, int tail)
{
    __shared__ float lds[3 * QTOT];           // planar: [c][r][col], 6912 B

    // swizzle: XCD k (blockIdx%8) gets patches [k*4096, (k+1)*4096) = image k
    int p = (blockIdx.x & 7) * (NPATCH / 8) + (blockIdx.x >> 3);
    int iw = p & 63;
    int ih = (p >> 6) & 63;
    int b  = p >> 12;
    int h0 = ih * 16 - 4;
    int w0 = iw * 16 - 4;
    int tid = threadIdx.x;

    const float* xb = x + (size_t)b * (3 * 1024 * 1024);

    bool edge = (ih == 0) | (ih == 63) | (iw == 0) | (iw == 63);
    if (!edge) {
        // interior: h0 in [12,988], w0 in [12,988] -> no reflect, 16B-aligned rows
        for (int j = tid; j < NV; j += 256) {
            int c   = j / 144;
            int rem = j - c * 144;
            int r   = rem / 6;
            int k   = rem - r * 6;
            const vfloat4 v = *(const vfloat4*)(xb + (c * 1024 + h0 + r) * 1024 + w0 + 4 * k);
            *(vfloat4*)(&lds[c * QTOT + r * PS + 4 * k]) = v;
        }
    } else {
        for (int j = tid; j < NV; j += 256) {
            int c   = j / 144;
            int rem = j - c * 144;
            int r   = rem / 6;
            int k   = rem - r * 6;
            int h = h0 + r;
            h = (h < 0) ? -h : ((h > 1023) ? 2046 - h : h);
            const float* rowp = xb + (c * 1024 + h) * 1024;
#pragma unroll
            for (int e = 0; e < 4; ++e) {
                int w = w0 + 4 * k + e;
                w = (w < 0) ? -w : ((w > 1023) ? 2046 - w : w);
                lds[c * QTOT + r * PS + 4 * k + e] = rowp[w];
            }
        }
    }
    __syncthreads();

    float* ob = out + (size_t)p * PATCH_F;
    for (int j = tid; j < NV; j += 256) {
        int f = 4 * j;
        vfloat4 v;
#pragma unroll
        for (int e = 0; e < 4; ++e) {
            int idx = f + e;              // output float index within patch
            int pix = idx / 3;            // pixel = pr*24+pc
            int c   = idx - pix * 3;
            v[e] = lds[c * QTOT + pix];   // bank = pix & 31 -> <=2-way, free
        }
        __builtin_nontemporal_store(v, (vfloat4*)(ob + f));
    }

    // trailing scalar outputs nH, nW
    if (blockIdx.x == 0 && tid < tail) {
        out[(size_t)PATCH_ELEMS_I + tid] = 64.0f;
    }
}

extern "C" void kernel_launch(void* const* d_in, const int* in_sizes, int n_in,
                              void* d_out, int out_size, void* d_ws, size_t ws_size,
                              hipStream_t stream)
{
    const float* x = (const float*)d_in[0];
    float* out = (float*)d_out;

    int tail = out_size - PATCH_ELEMS_I;
    if (tail < 0) tail = 0;
    if (tail > 256) tail = 256;

    patcher_kernel<<<NPATCH, 256, 0, stream>>>(x, out, tail);
}